// Round 3
// baseline (169.059 us; speedup 1.0000x reference)
//
#include <hip/hip_runtime.h>
#include <hip/hip_bf16.h>

#define MM 256
#define KK 4096
#define NN 32000
#define BN 64
#define BK 64
#define NT (KK / BK)   // 64 K-steps

typedef __bf16 bf16x8 __attribute__((ext_vector_type(8)));
typedef float f32x4 __attribute__((ext_vector_type(4)));

__device__ __forceinline__ unsigned pk(float a, float b) {
    unsigned short lo = __builtin_bit_cast(unsigned short, __float2bfloat16(a));
    unsigned short hi = __builtin_bit_cast(unsigned short, __float2bfloat16(b));
    return (unsigned)lo | ((unsigned)hi << 16);
}

// x fp32 [256][4096] -> bf16 (as ushort) in ws
__global__ void cvt_x_kernel(const float* __restrict__ x, unsigned short* __restrict__ xb) {
    int i = (blockIdx.x * 256 + threadIdx.x) * 8;
    float4 a = *(const float4*)(x + i);
    float4 b = *(const float4*)(x + i + 4);
    uint4 p;
    p.x = pk(a.x, a.y); p.y = pk(a.z, a.w);
    p.z = pk(b.x, b.y); p.w = pk(b.z, b.w);
    *(uint4*)(xb + i) = p;
}

// C[m][n] = sum_k x[m][k] * w[n][k]; BM=256 (all M), BN=64, BK=64.
// 512 threads = 8 waves, wave w owns rows [32w, 32w+32) x all 64 cols.
// x (bf16 in ws) read DIRECTLY from global/L2 (no LDS) -> LDS = W dbuf only
// (16 KB) -> 2 blocks/CU. W: depth-2 reg prefetch, counted vmcnt, 1 raw
// barrier/tile, XOR-swizzled LDS.
template <bool XB>
__global__ __launch_bounds__(512, 4) void gemm_kernel(
    const unsigned short* __restrict__ xb, const float* __restrict__ xf,
    const float* __restrict__ w, float* __restrict__ out) {
    __shared__ unsigned short wt[2][BN * 64];   // 2 x 8 KB

    const int tid  = threadIdx.x;
    const int lane = tid & 63;
    const int wid  = tid >> 6;   // 0..7 -> M slice
    const int l15  = lane & 15;
    const int lg   = lane >> 4;
    const int n0   = blockIdx.x * BN;

    // W staging: thread t -> row t>>3 (0..63), 8-col slot t&7 (32B of fp32)
    const int wrow  = tid >> 3;
    const int wslot = tid & 7;
    const float* wbase = w + (size_t)(n0 + wrow) * KK + wslot * 8;
    const int wsoff = wrow * 64 + ((wslot ^ (wrow & 7)) * 8);

    // A fragments: rows wid*32 + mi*16 + l15, k-chunk lg*8 within kf*32
    const int arow = wid * 32;

    f32x4 acc[2][4];
#pragma unroll
    for (int i = 0; i < 2; ++i)
#pragma unroll
        for (int j = 0; j < 4; ++j) acc[i][j] = f32x4{0.f, 0.f, 0.f, 0.f};

    float4 wA[2], wB[2];

    auto issueW = [&](int t, float4 (&wr)[2]) {
        const float* p = wbase + t * BK;
        wr[0] = *(const float4*)(p);
        wr[1] = *(const float4*)(p + 4);
    };
    auto stageW = [&](int pb, float4 (&wr)[2]) {
        uint4 v;
        v.x = pk(wr[0].x, wr[0].y); v.y = pk(wr[0].z, wr[0].w);
        v.z = pk(wr[1].x, wr[1].y); v.w = pk(wr[1].z, wr[1].w);
        *(uint4*)&wt[pb][wsoff] = v;
    };

    auto tile = [&](int pb, int t, int tpre, float4 (&wr)[2]) {
        // 1) stage W[t] (compiler emits counted vmcnt: only wr's loads drained)
        stageW(pb, wr);
        // 2) issue A[t] fragment loads from global bf16 (L2-resident)
        uint4 ar[2][2];
        float4 arf[2][2][2];
        const int ko = t * BK;
#pragma unroll
        for (int mi = 0; mi < 2; ++mi)
#pragma unroll
            for (int kf = 0; kf < 2; ++kf) {
                const size_t off = (size_t)(arow + mi * 16 + l15) * KK + ko + kf * 32 + lg * 8;
                if constexpr (XB) {
                    ar[mi][kf] = *(const uint4*)(xb + off);
                } else {
                    arf[mi][kf][0] = *(const float4*)(xf + off);
                    arf[mi][kf][1] = *(const float4*)(xf + off + 4);
                }
            }
        // 3) issue W[t+2] prefetch (stays in flight across the MFMA waits)
        if (tpre < NT) issueW(tpre, wr);
        // 4) LDS writes visible, then raw barrier (vmcnt NOT drained)
        __builtin_amdgcn_sched_barrier(0);
        asm volatile("s_waitcnt lgkmcnt(0)" ::: "memory");
        __builtin_amdgcn_s_barrier();
        // 5) compute
#pragma unroll
        for (int kf = 0; kf < 2; ++kf) {
            uint4 bfr[4];
#pragma unroll
            for (int ni = 0; ni < 4; ++ni) {
                const int r = ni * 16 + l15;
                bfr[ni] = *(const uint4*)&wt[pb][r * 64 + (((kf * 4 + lg) ^ (r & 7)) * 8)];
            }
#pragma unroll
            for (int mi = 0; mi < 2; ++mi) {
                uint4 a;
                if constexpr (XB) {
                    a = ar[mi][kf];
                } else {
                    a.x = pk(arf[mi][kf][0].x, arf[mi][kf][0].y);
                    a.y = pk(arf[mi][kf][0].z, arf[mi][kf][0].w);
                    a.z = pk(arf[mi][kf][1].x, arf[mi][kf][1].y);
                    a.w = pk(arf[mi][kf][1].z, arf[mi][kf][1].w);
                }
#pragma unroll
                for (int ni = 0; ni < 4; ++ni)
                    acc[mi][ni] = __builtin_amdgcn_mfma_f32_16x16x32_bf16(
                        __builtin_bit_cast(bf16x8, a),
                        __builtin_bit_cast(bf16x8, bfr[ni]), acc[mi][ni], 0, 0, 0);
            }
        }
    };

    issueW(0, wA);
    issueW(1, wB);

#pragma unroll 1
    for (int t = 0; t < NT; t += 2) {
        tile(0, t,     t + 2, wA);
        tile(1, t + 1, t + 3, wB);
    }

    // epilogue: per 16x16 tile, col = lane&15, row = (lane>>4)*4 + v
#pragma unroll
    for (int mi = 0; mi < 2; ++mi)
#pragma unroll
        for (int ni = 0; ni < 4; ++ni) {
            const int rowb = arow + mi * 16 + lg * 4;
            const int col  = n0 + ni * 16 + l15;
#pragma unroll
            for (int v = 0; v < 4; ++v)
                out[(size_t)(rowb + v) * NN + col] = acc[mi][ni][v];
        }
}

extern "C" void kernel_launch(void* const* d_in, const int* in_sizes, int n_in,
                              void* d_out, int out_size, void* d_ws, size_t ws_size,
                              hipStream_t stream) {
    const float* x = (const float*)d_in[0];
    const float* w = (const float*)d_in[1];
    float* out = (float*)d_out;
    unsigned short* xb = (unsigned short*)d_ws;

    if (ws_size >= (size_t)MM * KK * sizeof(unsigned short)) {
        cvt_x_kernel<<<512, 256, 0, stream>>>(x, xb);
        gemm_kernel<true><<<NN / BN, 512, 0, stream>>>(xb, x, w, out);
    } else {
        gemm_kernel<false><<<NN / BN, 512, 0, stream>>>(nullptr, x, w, out);
    }
}

// Round 4
// 162.415 us; speedup vs baseline: 1.0409x; 1.0409x over previous
//
#include <hip/hip_runtime.h>
#include <hip/hip_bf16.h>

#define MM 256
#define KK 4096
#define NN 32000
#define BN 64
#define BK 64
#define NT (KK / BK)   // 64 K-steps

typedef __bf16 bf16x8 __attribute__((ext_vector_type(8)));
typedef float f32x4 __attribute__((ext_vector_type(4)));

__device__ __forceinline__ unsigned pk(float a, float b) {
    unsigned short lo = __builtin_bit_cast(unsigned short, __float2bfloat16(a));
    unsigned short hi = __builtin_bit_cast(unsigned short, __float2bfloat16(b));
    return (unsigned)lo | ((unsigned)hi << 16);
}

__device__ __forceinline__ void dma16(const unsigned short* g, unsigned short* l) {
    __builtin_amdgcn_global_load_lds(
        (const __attribute__((address_space(1))) unsigned int*)g,
        (__attribute__((address_space(3))) unsigned int*)l, 16, 0, 0);
}

// xb layout: tile-major [t][row r][slot s] (slot = 8 ushorts), pre-swizzled:
// slot s of row r holds x[r][t*64 + (s ^ (r&7))*8 .. +8) as bf16.
// gemm DMAs tile t linearly into LDS; swizzled ds_read recovers chunks.
__global__ void cvt_x_kernel(const float* __restrict__ x, unsigned short* __restrict__ xb) {
    int g = blockIdx.x * 256 + threadIdx.x;   // chunk id, 131072 total
    int t = g >> 11;
    int d = g & 2047;
    int r = d >> 3;
    int cs = d & 7;
    int c = cs ^ (r & 7);
    const float* s = x + r * KK + t * 64 + c * 8;
    float4 a = *(const float4*)s;
    float4 b = *(const float4*)(s + 4);
    uint4 p;
    p.x = pk(a.x, a.y); p.y = pk(a.z, a.w);
    p.z = pk(b.x, b.y); p.w = pk(b.z, b.w);
    *(uint4*)(xb + (size_t)g * 8) = p;
}

// C[m][n] = sum_k x[m][k] * w[n][k]. BM=256 (all M: W fetched exactly once),
// BN=64, grid=500 (~2 blocks/CU). 256 thr = 4 waves; wave owns 16 cols x 256
// rows. W: global->reg (depth-2 prefetch) -> pk -> MFMA B-frag, NO LDS.
// x: bf16 from ws, global_load_lds into 2x32KB LDS dbuf, XOR-swizzled reads.
// One raw s_barrier per tile; uniform counted vmcnt(12); last tile peeled.
template <bool XB>
__global__ __launch_bounds__(256, 2) void gemm_kernel(
    const unsigned short* __restrict__ xb, const float* __restrict__ xf,
    const float* __restrict__ w, float* __restrict__ out) {
    __shared__ unsigned short xs[2][16384];   // 2 x 32 KB

    const int tid  = threadIdx.x;
    const int lane = tid & 63;
    const int wid  = tid >> 6;    // 0..3
    const int l15  = lane & 15;
    const int lg   = lane >> 4;
    const int n0   = blockIdx.x * BN;
    const int nw   = n0 + wid * 16;

    // W fragment source: lane l15 -> row nw+l15, lg -> 8-float k-chunk
    const float* wbase = w + (size_t)(nw + l15) * KK + lg * 8;

    f32x4 acc[16];
#pragma unroll
    for (int i = 0; i < 16; ++i) acc[i] = f32x4{0.f, 0.f, 0.f, 0.f};

    if constexpr (!XB) {
        // correctness fallback (ws too small): naive, x fp32 direct
#pragma unroll 1
        for (int t = 0; t < NT; ++t) {
            const float* wp = wbase + t * 64;
            float4 w0 = *(const float4*)(wp);
            float4 w1 = *(const float4*)(wp + 4);
            float4 w2 = *(const float4*)(wp + 32);
            float4 w3 = *(const float4*)(wp + 36);
            uint4 bf[2];
            bf[0].x = pk(w0.x, w0.y); bf[0].y = pk(w0.z, w0.w);
            bf[0].z = pk(w1.x, w1.y); bf[0].w = pk(w1.z, w1.w);
            bf[1].x = pk(w2.x, w2.y); bf[1].y = pk(w2.z, w2.w);
            bf[1].z = pk(w3.x, w3.y); bf[1].w = pk(w3.z, w3.w);
#pragma unroll
            for (int kf = 0; kf < 2; ++kf) {
                uint4 bfr = bf[kf];
#pragma unroll
                for (int mi = 0; mi < 16; ++mi) {
                    const float* xp = xf + (size_t)(mi * 16 + l15) * KK + t * 64 + kf * 32 + lg * 8;
                    float4 a0 = *(const float4*)xp;
                    float4 a1 = *(const float4*)(xp + 4);
                    uint4 af;
                    af.x = pk(a0.x, a0.y); af.y = pk(a0.z, a0.w);
                    af.z = pk(a1.x, a1.y); af.w = pk(a1.z, a1.w);
                    acc[mi] = __builtin_amdgcn_mfma_f32_16x16x32_bf16(
                        __builtin_bit_cast(bf16x8, af),
                        __builtin_bit_cast(bf16x8, bfr), acc[mi], 0, 0, 0);
                }
            }
        }
    } else {
        float4 wA[4], wB[4];

        auto issue_w = [&](int t, float4 (&wr)[4]) {
            const float* p = wbase + t * 64;
            wr[0] = *(const float4*)(p);
            wr[1] = *(const float4*)(p + 4);
            wr[2] = *(const float4*)(p + 32);
            wr[3] = *(const float4*)(p + 36);
        };
        auto issue_dma = [&](int t, int p) {
            // wave wid covers LDS bytes [wid*8K, wid*8K+8K) of buffer p, 8 DMAs
#pragma unroll
            for (int j = 0; j < 8; ++j) {
                const unsigned short* gp =
                    xb + (size_t)t * 16384 + wid * 4096 + j * 512 + lane * 8;
                unsigned short* lp = &xs[p][wid * 4096 + j * 512];
                dma16(gp, lp);
            }
        };

        issue_w(0, wA);       // oldest
        issue_dma(0, 0);
        issue_w(1, wB);

#pragma unroll 1
        for (int t = 0; t < NT - 1; ++t) {
            __builtin_amdgcn_s_barrier();            // all waves done compute(t-1)
            __builtin_amdgcn_sched_barrier(0);
            issue_dma(t + 1, (t + 1) & 1);
            __builtin_amdgcn_sched_barrier(0);
            // drain dma[t] + W[t]; keep W[t+1](4) + dma[t+1](8) in flight
            asm volatile("s_waitcnt vmcnt(12)" ::: "memory");
            __builtin_amdgcn_sched_barrier(0);
            if ((t & 1) == 0) {
                __builtin_amdgcn_s_setprio(1);
#pragma unroll
                for (int kf = 0; kf < 2; ++kf) {
                    uint4 bfr;
                    bfr.x = pk(wA[kf * 2].x, wA[kf * 2].y);
                    bfr.y = pk(wA[kf * 2].z, wA[kf * 2].w);
                    bfr.z = pk(wA[kf * 2 + 1].x, wA[kf * 2 + 1].y);
                    bfr.w = pk(wA[kf * 2 + 1].z, wA[kf * 2 + 1].w);
#pragma unroll
                    for (int mi = 0; mi < 16; ++mi) {
                        const int r = mi * 16 + l15;
                        const int c = kf * 4 + lg;
                        uint4 af = *(const uint4*)&xs[0][r * 64 + ((c ^ (r & 7)) * 8)];
                        acc[mi] = __builtin_amdgcn_mfma_f32_16x16x32_bf16(
                            __builtin_bit_cast(bf16x8, af),
                            __builtin_bit_cast(bf16x8, bfr), acc[mi], 0, 0, 0);
                    }
                }
                __builtin_amdgcn_s_setprio(0);
                if (t + 2 < NT) issue_w(t + 2, wA);
            } else {
                __builtin_amdgcn_s_setprio(1);
#pragma unroll
                for (int kf = 0; kf < 2; ++kf) {
                    uint4 bfr;
                    bfr.x = pk(wB[kf * 2].x, wB[kf * 2].y);
                    bfr.y = pk(wB[kf * 2].z, wB[kf * 2].w);
                    bfr.z = pk(wB[kf * 2 + 1].x, wB[kf * 2 + 1].y);
                    bfr.w = pk(wB[kf * 2 + 1].z, wB[kf * 2 + 1].w);
#pragma unroll
                    for (int mi = 0; mi < 16; ++mi) {
                        const int r = mi * 16 + l15;
                        const int c = kf * 4 + lg;
                        uint4 af = *(const uint4*)&xs[1][r * 64 + ((c ^ (r & 7)) * 8)];
                        acc[mi] = __builtin_amdgcn_mfma_f32_16x16x32_bf16(
                            __builtin_bit_cast(bf16x8, af),
                            __builtin_bit_cast(bf16x8, bfr), acc[mi], 0, 0, 0);
                    }
                }
                __builtin_amdgcn_s_setprio(0);
                if (t + 2 < NT) issue_w(t + 2, wB);
            }
        }
        // t = NT-1 (odd): only dma[NT-1] outstanding
        __builtin_amdgcn_s_barrier();
        __builtin_amdgcn_sched_barrier(0);
        asm volatile("s_waitcnt vmcnt(0)" ::: "memory");
        __builtin_amdgcn_sched_barrier(0);
        __builtin_amdgcn_s_setprio(1);
#pragma unroll
        for (int kf = 0; kf < 2; ++kf) {
            uint4 bfr;
            bfr.x = pk(wB[kf * 2].x, wB[kf * 2].y);
            bfr.y = pk(wB[kf * 2].z, wB[kf * 2].w);
            bfr.z = pk(wB[kf * 2 + 1].x, wB[kf * 2 + 1].y);
            bfr.w = pk(wB[kf * 2 + 1].z, wB[kf * 2 + 1].w);
#pragma unroll
            for (int mi = 0; mi < 16; ++mi) {
                const int r = mi * 16 + l15;
                const int c = kf * 4 + lg;
                uint4 af = *(const uint4*)&xs[1][r * 64 + ((c ^ (r & 7)) * 8)];
                acc[mi] = __builtin_amdgcn_mfma_f32_16x16x32_bf16(
                    __builtin_bit_cast(bf16x8, af),
                    __builtin_bit_cast(bf16x8, bfr), acc[mi], 0, 0, 0);
            }
        }
        __builtin_amdgcn_s_setprio(0);
    }

    // epilogue: per 16x16 tile, col = lane&15, row = (lane>>4)*4 + v
#pragma unroll
    for (int mi = 0; mi < 16; ++mi) {
        const int rowb = mi * 16 + lg * 4;
        const int col  = nw + l15;
#pragma unroll
        for (int v = 0; v < 4; ++v)
            out[(size_t)(rowb + v) * NN + col] = acc[mi][v];
    }
}

extern "C" void kernel_launch(void* const* d_in, const int* in_sizes, int n_in,
                              void* d_out, int out_size, void* d_ws, size_t ws_size,
                              hipStream_t stream) {
    const float* x = (const float*)d_in[0];
    const float* w = (const float*)d_in[1];
    float* out = (float*)d_out;
    unsigned short* xb = (unsigned short*)d_ws;

    if (ws_size >= (size_t)MM * KK * sizeof(unsigned short)) {
        cvt_x_kernel<<<512, 256, 0, stream>>>(x, xb);
        gemm_kernel<true><<<NN / BN, 256, 0, stream>>>(xb, x, w, out);
    } else {
        gemm_kernel<false><<<NN / BN, 256, 0, stream>>>(nullptr, x, w, out);
    }
}

// Round 5
// 146.187 us; speedup vs baseline: 1.1565x; 1.1110x over previous
//
#include <hip/hip_runtime.h>
#include <hip/hip_bf16.h>

#define MM 256
#define KK 4096
#define NN 32000
#define BN 64
#define BK 64
#define NT (KK / BK)   // 64 K-steps

typedef __bf16 bf16x8 __attribute__((ext_vector_type(8)));
typedef float f32x4 __attribute__((ext_vector_type(4)));

__device__ __forceinline__ unsigned pk(float a, float b) {
    unsigned short lo = __builtin_bit_cast(unsigned short, __float2bfloat16(a));
    unsigned short hi = __builtin_bit_cast(unsigned short, __float2bfloat16(b));
    return (unsigned)lo | ((unsigned)hi << 16);
}

__device__ __forceinline__ void dma16(const unsigned short* g, unsigned short* l) {
    __builtin_amdgcn_global_load_lds(
        (const __attribute__((address_space(1))) unsigned int*)g,
        (__attribute__((address_space(3))) unsigned int*)l, 16, 0, 0);
}

// xb layout: tile-major [t][row r][slot s] (slot = 8 ushorts), pre-swizzled:
// slot s of row r holds x[r][t*64 + (s ^ (r&7))*8 .. +8) as bf16.
// gemm DMAs tile t LINEARLY into LDS; swizzled ds_read recovers chunks.
__global__ void cvt_x_kernel(const float* __restrict__ x, unsigned short* __restrict__ xb) {
    int g = blockIdx.x * 256 + threadIdx.x;   // chunk id, 131072 total
    int t = g >> 11;
    int d = g & 2047;
    int r = d >> 3;
    int cs = d & 7;
    int c = cs ^ (r & 7);
    const float* s = x + r * KK + t * 64 + c * 8;
    float4 a = *(const float4*)s;
    float4 b = *(const float4*)(s + 4);
    uint4 p;
    p.x = pk(a.x, a.y); p.y = pk(a.z, a.w);
    p.z = pk(b.x, b.y); p.w = pk(b.z, b.w);
    *(uint4*)(xb + (size_t)g * 8) = p;
}

// C[m][n] = sum_k x[m][k] * w[n][k]. BM=256 (W fetched exactly once), BN=64,
// grid=500 -> 2 blocks/CU (80 KB LDS each). 512 thr = 8 waves as 4M x 2N:
// wave (wm,wn) owns rows [64*wm,64*wm+64) x cols [32*wn,32*wn+32).
// x: ws bf16 -> global_load_lds dbuf (2x32KB). W: fp32->reg depth-2 -> pk ->
// LDS dbuf (2x8KB). One raw s_barrier/tile; own-vmcnt drained BEFORE barrier
// (race-free publication); counted vmcnt(4) keeps next W + next DMA in flight.
template <bool XB>
__global__ __launch_bounds__(512, 4) void gemm_kernel(
    const unsigned short* __restrict__ xb, const float* __restrict__ xf,
    const float* __restrict__ w, float* __restrict__ out) {
    __shared__ unsigned short xs[2][16384];  // 2 x 32 KB
    __shared__ unsigned short wt[2][4096];   // 2 x 8 KB

    const int tid  = threadIdx.x;
    const int lane = tid & 63;
    const int wid  = tid >> 6;    // 0..7
    const int wm   = wid >> 1;    // 0..3 -> 64-row slice
    const int wn   = wid & 1;     // 0..1 -> 32-col slice
    const int l15  = lane & 15;
    const int lg   = lane >> 4;
    const int n0   = blockIdx.x * BN;

    // W staging: thread -> row tid>>3 (0..63), slot tid&7 (8 floats = 32B)
    const int wrow  = tid >> 3;
    const int wslot = tid & 7;
    const float* wsrc = w + (size_t)(n0 + wrow) * KK + wslot * 8;
    const int wdst = wrow * 64 + ((wslot ^ (wrow & 7)) * 8);

    f32x4 acc[4][2];
#pragma unroll
    for (int i = 0; i < 4; ++i)
#pragma unroll
        for (int j = 0; j < 2; ++j) acc[i][j] = f32x4{0.f, 0.f, 0.f, 0.f};

    auto compute = [&](int pb) {
        __builtin_amdgcn_s_setprio(1);
#pragma unroll
        for (int kf = 0; kf < 2; ++kf) {
            const int c = kf * 4 + lg;
            const int sw = ((c ^ (l15 & 7)) * 8);
            uint4 bfr[2];
#pragma unroll
            for (int ni = 0; ni < 2; ++ni)
                bfr[ni] = *(const uint4*)&wt[pb][(wn * 32 + ni * 16 + l15) * 64 + sw];
            uint4 af[4];
#pragma unroll
            for (int mi = 0; mi < 4; ++mi)
                af[mi] = *(const uint4*)&xs[pb][(wm * 64 + mi * 16 + l15) * 64 + sw];
#pragma unroll
            for (int mi = 0; mi < 4; ++mi)
#pragma unroll
                for (int ni = 0; ni < 2; ++ni)
                    acc[mi][ni] = __builtin_amdgcn_mfma_f32_16x16x32_bf16(
                        __builtin_bit_cast(bf16x8, af[mi]),
                        __builtin_bit_cast(bf16x8, bfr[ni]), acc[mi][ni], 0, 0, 0);
        }
        __builtin_amdgcn_s_setprio(0);
    };

    if constexpr (!XB) {
        // correctness fallback (ws too small): direct global reads, no LDS
#pragma unroll 1
        for (int t = 0; t < NT; ++t) {
#pragma unroll
            for (int kf = 0; kf < 2; ++kf) {
                const int k = t * 64 + kf * 32 + lg * 8;
                uint4 bfr[2];
#pragma unroll
                for (int ni = 0; ni < 2; ++ni) {
                    const float* p = w + (size_t)(n0 + wn * 32 + ni * 16 + l15) * KK + k;
                    float4 a0 = *(const float4*)p;
                    float4 a1 = *(const float4*)(p + 4);
                    bfr[ni].x = pk(a0.x, a0.y); bfr[ni].y = pk(a0.z, a0.w);
                    bfr[ni].z = pk(a1.x, a1.y); bfr[ni].w = pk(a1.z, a1.w);
                }
#pragma unroll
                for (int mi = 0; mi < 4; ++mi) {
                    const float* p = xf + (size_t)(wm * 64 + mi * 16 + l15) * KK + k;
                    float4 a0 = *(const float4*)p;
                    float4 a1 = *(const float4*)(p + 4);
                    uint4 af;
                    af.x = pk(a0.x, a0.y); af.y = pk(a0.z, a0.w);
                    af.z = pk(a1.x, a1.y); af.w = pk(a1.z, a1.w);
#pragma unroll
                    for (int ni = 0; ni < 2; ++ni)
                        acc[mi][ni] = __builtin_amdgcn_mfma_f32_16x16x32_bf16(
                            __builtin_bit_cast(bf16x8, af),
                            __builtin_bit_cast(bf16x8, bfr[ni]), acc[mi][ni], 0, 0, 0);
                }
            }
        }
    } else {
        float4 wrA[2], wrB[2];

        auto issueW = [&](int t, float4 (&wr)[2]) {
            const float* p = wsrc + t * BK;
            wr[0] = *(const float4*)(p);
            wr[1] = *(const float4*)(p + 4);
        };
        auto stageW = [&](int pb, float4 (&wr)[2]) {
            uint4 v;
            v.x = pk(wr[0].x, wr[0].y); v.y = pk(wr[0].z, wr[0].w);
            v.z = pk(wr[1].x, wr[1].y); v.w = pk(wr[1].z, wr[1].w);
            *(uint4*)&wt[pb][wdst] = v;
        };
        auto issue_dma = [&](int t, int pb) {
            // 4 rounds x 512 thr x 16B = 32 KB; wave slice uniform base
#pragma unroll
            for (int j = 0; j < 4; ++j) {
                const unsigned short* gp =
                    xb + (size_t)t * 16384 + j * 4096 + wid * 512 + lane * 8;
                unsigned short* lp = &xs[pb][j * 4096 + wid * 512];
                dma16(gp, lp);
            }
        };

        // tile body: vmcnt order per tile is [W(t), dma(t), W(t+1)] on entry.
        auto tile_body = [&](int pb, int t, float4 (&wr)[2]) {
            stageW(pb, wr);                        // compiler waits vmcnt for wr=W(t)
            __builtin_amdgcn_sched_barrier(0);
            asm volatile("s_waitcnt vmcnt(4)" ::: "memory");   // drain own dma(t); keep W(t+1)
            asm volatile("s_waitcnt lgkmcnt(0)" ::: "memory"); // own ds_write visible
            __builtin_amdgcn_sched_barrier(0);
            __builtin_amdgcn_s_barrier();          // all waves: xs[pb], wt[pb] ready
            const int tn = (t + 1 < NT) ? t + 1 : NT - 1;
            issue_dma(tn, pb ^ 1);                 // safe: compute(t-1) finished pre-barrier
            __builtin_amdgcn_sched_barrier(0);
            const int tw = (t + 2 < NT) ? t + 2 : NT - 1;
            issueW(tw, wr);                        // refill regs for tile t+2 (clamped: uniform counts)
            __builtin_amdgcn_sched_barrier(0);
            compute(pb);
        };

        issueW(0, wrA);
        issue_dma(0, 0);
        issueW(1, wrB);

#pragma unroll 1
        for (int t = 0; t < NT; t += 2) {
            tile_body(0, t, wrA);
            tile_body(1, t + 1, wrB);
        }
        // drain junk tail prefetches before LDS goes away / epilogue
        asm volatile("s_waitcnt vmcnt(0)" ::: "memory");
    }

    // epilogue: per 16x16 tile, col = lane&15, row = (lane>>4)*4 + v
#pragma unroll
    for (int mi = 0; mi < 4; ++mi)
#pragma unroll
        for (int ni = 0; ni < 2; ++ni) {
            const int rowb = wm * 64 + mi * 16 + lg * 4;
            const int col  = n0 + wn * 32 + ni * 16 + l15;
#pragma unroll
            for (int v = 0; v < 4; ++v)
                out[(size_t)(rowb + v) * NN + col] = acc[mi][ni][v];
        }
}

extern "C" void kernel_launch(void* const* d_in, const int* in_sizes, int n_in,
                              void* d_out, int out_size, void* d_ws, size_t ws_size,
                              hipStream_t stream) {
    const float* x = (const float*)d_in[0];
    const float* w = (const float*)d_in[1];
    float* out = (float*)d_out;
    unsigned short* xb = (unsigned short*)d_ws;

    if (ws_size >= (size_t)MM * KK * sizeof(unsigned short)) {
        cvt_x_kernel<<<512, 256, 0, stream>>>(x, xb);
        gemm_kernel<true><<<NN / BN, 512, 0, stream>>>(xb, x, w, out);
    } else {
        gemm_kernel<false><<<NN / BN, 512, 0, stream>>>(nullptr, x, w, out);
    }
}